// Round 3
// baseline (413.218 us; speedup 1.0000x reference)
//
#include <hip/hip_runtime.h>

// Bahdanau attention fused kernel for MI355X (gfx950).
// scores[b][s] = softmax_s( v . tanh( hb[b,:] + enc[s,b,:] @ We ) )
// hb[b][n] = attn_b[n] + hidden[b,:] @ Wh   (exact f32, tiny)
// Big GEMM done in f16 MFMA (16x16x32), f32 accumulate.
// R3: prefetch-distance-2, 3 LDS buffers, raw s_barrier + counted vmcnt(6)
//     (T4: never drain vmcnt to 0 in the main loop).

typedef _Float16 f16;
typedef _Float16 half8 __attribute__((ext_vector_type(8)));
typedef float f32x4 __attribute__((ext_vector_type(4)));

#define KDIM 1024
#define NDIM 1024
#define SEQ  2048
#define NB   32

typedef __attribute__((address_space(1))) void gvoid;
typedef __attribute__((address_space(3))) void svoid;

__device__ __forceinline__ void gload_lds16(const void* g, void* l) {
    __builtin_amdgcn_global_load_lds((const gvoid*)g, (svoid*)l, 16, 0, 0);
}

// ---------------------------------------------------------------------------
// prep_w: transpose + f16-convert + tile + swizzle the enc-half of attn_w.
// Tile t = ks*2 + pass; tile = LDS image of the [512 n][32 k] chunk:
// 16B block p = nloc*4 + ((kblk + (nloc>>1)) & 3).
// ---------------------------------------------------------------------------
__global__ __launch_bounds__(256) void prep_w(const float* __restrict__ w,
                                              f16* __restrict__ wt) {
    int idx   = blockIdx.x * 256 + threadIdx.x;   // 0..131071
    int t     = idx >> 11;                        // tile 0..63
    int unit  = idx & 2047;
    int nloc  = unit >> 2;                        // 0..511
    int kblk  = unit & 3;
    int kstep = t >> 1, npass = t & 1;
    int n_g   = npass * 512 + nloc;
    int kbase = kstep * 32 + kblk * 8;
    half8 h;
#pragma unroll
    for (int kk = 0; kk < 8; ++kk)
        h[kk] = (f16)w[(size_t)(1024 + kbase + kk) * 1024 + n_g];
    int p = nloc * 4 + ((kblk + (nloc >> 1)) & 3);
    *(half8*)&wt[(size_t)t * 16384 + p * 8] = h;
}

// ---------------------------------------------------------------------------
// prep_hb: hb[b][n] = attn_b[n] + sum_k hidden[b][k] * attn_w[k][n]  (f32)
// ---------------------------------------------------------------------------
__global__ __launch_bounds__(256) void prep_hb(const float* __restrict__ hidden,
                                               const float* __restrict__ attn_w,
                                               const float* __restrict__ attn_b,
                                               float* __restrict__ hb) {
    int b = blockIdx.x >> 2;
    int n = (blockIdx.x & 3) * 256 + threadIdx.x;
    const float* h = hidden + (size_t)b * 1024;
    float acc = attn_b[n];
#pragma unroll 8
    for (int k = 0; k < 1024; ++k)
        acc += h[k] * attn_w[(size_t)k * 1024 + n];
    hb[(size_t)b * 1024 + n] = acc;
}

// ---------------------------------------------------------------------------
// fused_energy: per wg 128 flat rows; flat tile t=0..63 (pass = t>>5, ks=t&31).
// 8 waves (2M x 4N), wave tile 64x128, frags 4(M) x 8(N).
// Prefetch distance 2, 3 LDS buffers, counted vmcnt — 6 loads always in flight.
// ---------------------------------------------------------------------------
__global__ __launch_bounds__(512, 2)
void fused_energy(const float* __restrict__ enc, const f16* __restrict__ wt,
                  const float* __restrict__ hb, const float* __restrict__ vvec,
                  float* __restrict__ out) {
    __shared__ f16 Ws[3][512 * 32];   // 3 x 32 KB
    __shared__ f16 As[3][128 * 32];   // 3 x 8 KB
    __shared__ float red[4][128];

    const int tid  = threadIdx.x;
    const int lane = tid & 63;
    const int wv   = tid >> 6;     // 0..7
    const int wm   = wv >> 2;      // 0..1
    const int wn   = wv & 3;       // 0..3
    const int l15  = lane & 15;
    const int l4   = lane >> 4;
    const int wgrow = blockIdx.x * 128;

    // A staging: thread -> (row, kblk); 8 f32 -> 8 f16 -> one ds_write_b128
    const int ar  = tid >> 2;      // 0..127
    const int akb = tid & 3;
    const float* aG = enc + (size_t)(wgrow + ar) * KDIM + akb * 8;
    const int aDstByte = (ar * 4 + ((akb + (ar >> 1)) & 3)) * 16;

    // W staging: wave wv owns 4 x 1KB segments (gload_lds 16B/lane)
    const int wLdsOff = wv * 4096 + lane * 16;

    // fragment LDS byte offsets (swizzled)
    int aOffB[4], bOffB[8];
#pragma unroll
    for (int mi = 0; mi < 4; ++mi) {
        int r = wm * 64 + mi * 16 + l15;
        aOffB[mi] = (r * 4 + ((l4 + (r >> 1)) & 3)) * 16;
    }
#pragma unroll
    for (int nj = 0; nj < 8; ++nj) {
        int n = wn * 128 + nj * 16 + l15;
        bOffB[nj] = (n * 4 + ((l4 + (n >> 1)) & 3)) * 16;
    }

    float part[4][4];
#pragma unroll
    for (int mi = 0; mi < 4; ++mi)
#pragma unroll
        for (int rg = 0; rg < 4; ++rg) part[mi][rg] = 0.f;

    const f32x4 zero = {0.f, 0.f, 0.f, 0.f};
    f32x4 acc[4][8];
#pragma unroll
    for (int mi = 0; mi < 4; ++mi)
#pragma unroll
        for (int nj = 0; nj < 8; ++nj) acc[mi][nj] = zero;

    f32x4 aEv0, aEv1, aOd0, aOd1;   // A-regs, parity by tile index

    // ---- prologue: stage tiles 0 (buf0) and 1 (buf1); write As[0] ----
    {
        const char* w0 = (const char*)wt + wLdsOff;                 // tile 0
        char* d0 = (char*)&Ws[0][0] + wLdsOff;
        gload_lds16(w0,        d0);
        gload_lds16(w0 + 1024, d0 + 1024);
        gload_lds16(w0 + 2048, d0 + 2048);
        gload_lds16(w0 + 3072, d0 + 3072);
        aEv0 = *(const f32x4*)aG;
        aEv1 = *(const f32x4*)(aG + 4);
        const char* w1 = (const char*)wt + (size_t)2 * 32768 + wLdsOff;  // tile 1 -> wtIdx 2
        char* d1 = (char*)&Ws[1][0] + wLdsOff;
        gload_lds16(w1,        d1);
        gload_lds16(w1 + 1024, d1 + 1024);
        gload_lds16(w1 + 2048, d1 + 2048);
        gload_lds16(w1 + 3072, d1 + 3072);
        aOd0 = *(const f32x4*)(aG + 32);
        aOd1 = *(const f32x4*)(aG + 36);
        // convert A(0) -> As[0]  (compiler waits vmcnt<=6: W0+A0 done, W1+A1 fly)
        asm volatile("s_waitcnt vmcnt(6)" ::: "memory");
        half8 ah;
#pragma unroll
        for (int j = 0; j < 4; ++j) { ah[j] = (f16)aEv0[j]; ah[4 + j] = (f16)aEv1[j]; }
        *(half8*)((char*)&As[0][0] + aDstByte) = ah;
    }
    asm volatile("s_waitcnt lgkmcnt(0)" ::: "memory");
    __builtin_amdgcn_s_barrier();

    // Per step t: issue tile t+2 (6 vmem ops), vmcnt(6) => tile t+1's ops done
    // (cross-wave W invariant), convert A(t+1), compute tile t, lgkm0+barrier.
#define KSTEP(T, ALD0, ALD1, ACV0, ACV1)                                      \
  {                                                                           \
    const int t_ = (T);                                                       \
    if (t_ < 62) {                                                            \
      const int tn = t_ + 2;                                                  \
      const int wi = (tn & 31) * 2 + (tn >> 5);                               \
      const char* ws_ = (const char*)wt + (size_t)wi * 32768 + wLdsOff;       \
      char* wd_ = (char*)&Ws[tn % 3][0] + wLdsOff;                            \
      gload_lds16(ws_,        wd_);                                           \
      gload_lds16(ws_ + 1024, wd_ + 1024);                                    \
      gload_lds16(ws_ + 2048, wd_ + 2048);                                    \
      gload_lds16(ws_ + 3072, wd_ + 3072);                                    \
      ALD0 = *(const f32x4*)(aG + (tn & 31) * 32);                            \
      ALD1 = *(const f32x4*)(aG + (tn & 31) * 32 + 4);                        \
      asm volatile("s_waitcnt vmcnt(6)" ::: "memory");                        \
    } else {                                                                  \
      asm volatile("s_waitcnt vmcnt(0)" ::: "memory");                        \
    }                                                                         \
    if (t_ < 63) {                                                            \
      half8 ah_;                                                              \
      _Pragma("unroll") for (int j = 0; j < 4; ++j) {                         \
        ah_[j] = (f16)ACV0[j]; ah_[4 + j] = (f16)ACV1[j];                     \
      }                                                                       \
      *(half8*)((char*)&As[(t_ + 1) % 3][0] + aDstByte) = ah_;                \
    }                                                                         \
    {                                                                         \
      const char* wb_ = (const char*)&Ws[t_ % 3][0];                          \
      const char* ab_ = (const char*)&As[t_ % 3][0];                          \
      half8 bf_[8];                                                           \
      _Pragma("unroll") for (int nj = 0; nj < 8; ++nj)                        \
        bf_[nj] = *(const half8*)(wb_ + bOffB[nj]);                           \
      _Pragma("unroll") for (int mi = 0; mi < 4; ++mi) {                      \
        half8 af_ = *(const half8*)(ab_ + aOffB[mi]);                         \
        _Pragma("unroll") for (int nj = 0; nj < 8; ++nj)                      \
          acc[mi][nj] = __builtin_amdgcn_mfma_f32_16x16x32_f16(               \
              af_, bf_[nj], acc[mi][nj], 0, 0, 0);                            \
      }                                                                       \
    }                                                                         \
    asm volatile("s_waitcnt lgkmcnt(0)" ::: "memory");                        \
    __builtin_amdgcn_s_barrier();                                             \
  }

#define EPILOGUE(P)                                                           \
  {                                                                           \
    const int nbase = (P) * 512 + wn * 128;                                   \
    float vv[8];                                                              \
    _Pragma("unroll") for (int nj = 0; nj < 8; ++nj)                          \
      vv[nj] = vvec[nbase + nj * 16 + l15];                                   \
    _Pragma("unroll") for (int mi = 0; mi < 4; ++mi) {                        \
      _Pragma("unroll") for (int rg = 0; rg < 4; ++rg) {                      \
        int rl = wm * 64 + mi * 16 + l4 * 4 + rg;                             \
        const float* hbrow = hb + (size_t)(rl & 31) * NDIM + nbase + l15;     \
        float sum = 0.f;                                                      \
        _Pragma("unroll") for (int nj = 0; nj < 8; ++nj) {                    \
          float e  = acc[mi][nj][rg] + hbrow[nj * 16];                        \
          float e2 = __expf(2.f * e);                                         \
          sum += (1.f - 2.f / (e2 + 1.f)) * vv[nj];                           \
        }                                                                     \
        part[mi][rg] += sum;                                                  \
      }                                                                       \
    }                                                                         \
  }

    for (int tt = 0; tt < 32; tt += 2) {
        KSTEP(tt,     aEv0, aEv1, aOd0, aOd1);   // even t: load->even, cvt odd
        KSTEP(tt + 1, aOd0, aOd1, aEv0, aEv1);   // odd t: load->odd, cvt even
    }
    EPILOGUE(0);
#pragma unroll
    for (int mi = 0; mi < 4; ++mi)
#pragma unroll
        for (int nj = 0; nj < 8; ++nj) acc[mi][nj] = zero;
    for (int tt = 32; tt < 64; tt += 2) {
        KSTEP(tt,     aEv0, aEv1, aOd0, aOd1);
        KSTEP(tt + 1, aOd0, aOd1, aEv0, aEv1);
    }
    EPILOGUE(1);
#undef KSTEP
#undef EPILOGUE

    // reduce over the 16 lanes holding different n-columns of the same row
#pragma unroll
    for (int mi = 0; mi < 4; ++mi) {
#pragma unroll
        for (int rg = 0; rg < 4; ++rg) {
            float p = part[mi][rg];
            p += __shfl_xor(p, 1);
            p += __shfl_xor(p, 2);
            p += __shfl_xor(p, 4);
            p += __shfl_xor(p, 8);
            if (l15 == 0) red[wn][wm * 64 + mi * 16 + l4 * 4 + rg] = p;
        }
    }
    __syncthreads();
    if (tid < 128) {
        float s = red[0][tid] + red[1][tid] + red[2][tid] + red[3][tid];
        int rG = wgrow + tid;                  // flat row = s*32 + b
        out[(size_t)(rG & 31) * SEQ + (rG >> 5)] = s;   // raw score -> out[b][s]
    }
}

// ---------------------------------------------------------------------------
// softmax over S=2048 per batch row, in-place on out
// ---------------------------------------------------------------------------
__global__ __launch_bounds__(256) void softmax_rows(float* __restrict__ out) {
    const int b = blockIdx.x;
    float* row = out + (size_t)b * SEQ;
    const int tid  = threadIdx.x;
    const int lane = tid & 63;
    const int wv   = tid >> 6;
    __shared__ float sred[4];
    __shared__ float ssum[4];
    float x[8];
    float mx = -3.4e38f;
#pragma unroll
    for (int j = 0; j < 8; ++j) { x[j] = row[tid + j * 256]; mx = fmaxf(mx, x[j]); }
#pragma unroll
    for (int o = 1; o < 64; o <<= 1) mx = fmaxf(mx, __shfl_xor(mx, o));
    if (lane == 0) sred[wv] = mx;
    __syncthreads();
    mx = fmaxf(fmaxf(sred[0], sred[1]), fmaxf(sred[2], sred[3]));
    float s = 0.f;
#pragma unroll
    for (int j = 0; j < 8; ++j) { x[j] = __expf(x[j] - mx); s += x[j]; }
#pragma unroll
    for (int o = 1; o < 64; o <<= 1) s += __shfl_xor(s, o);
    if (lane == 0) ssum[wv] = s;
    __syncthreads();
    s = ssum[0] + ssum[1] + ssum[2] + ssum[3];
    float inv = 1.f / s;
#pragma unroll
    for (int j = 0; j < 8; ++j) row[tid + j * 256] = x[j] * inv;
}

extern "C" void kernel_launch(void* const* d_in, const int* in_sizes, int n_in,
                              void* d_out, int out_size, void* d_ws, size_t ws_size,
                              hipStream_t stream) {
    const float* hidden = (const float*)d_in[0];   // [32][1024]
    const float* enc    = (const float*)d_in[1];   // [2048][32][1024]
    const float* attn_w = (const float*)d_in[2];   // [2048][1024]
    const float* attn_b = (const float*)d_in[3];   // [1024]
    const float* v      = (const float*)d_in[4];   // [1024]
    float* out = (float*)d_out;                    // [32][2048]

    f16*   wt = (f16*)d_ws;                        // 2 MB tiled/swizzled We
    float* hb = (float*)((char*)d_ws + (2u << 20)); // 128 KB

    prep_w<<<512, 256, 0, stream>>>(attn_w, wt);
    prep_hb<<<128, 256, 0, stream>>>(hidden, attn_w, attn_b, hb);
    fused_energy<<<512, 512, 0, stream>>>(enc, wt, hb, v, out);
    softmax_rows<<<32, 256, 0, stream>>>(out);
}

// Round 4
// 267.279 us; speedup vs baseline: 1.5460x; 1.5460x over previous
//
#include <hip/hip_runtime.h>

// Bahdanau attention fused kernel for MI355X (gfx950).
// scores[b][s] = softmax_s( v . tanh( hb[b,:] + enc[s,b,:] @ We ) )
// hb[b][n] = attn_b[n] + hidden[b,:] @ Wh   (exact f32, tiny)
// Big GEMM done in f16 MFMA (16x16x32), f32 accumulate.
// R4: back to R2's proven double-buffer loop; 256-thr blocks, 64-row tiles,
//     2 blocks/CU for cross-block latency hiding; setprio around MFMA.

typedef _Float16 f16;
typedef _Float16 half8 __attribute__((ext_vector_type(8)));
typedef float f32x4 __attribute__((ext_vector_type(4)));

#define KDIM 1024
#define NDIM 1024
#define SEQ  2048
#define NB   32

typedef __attribute__((address_space(1))) void gvoid;
typedef __attribute__((address_space(3))) void svoid;

__device__ __forceinline__ void gload_lds16(const void* g, void* l) {
    __builtin_amdgcn_global_load_lds((const gvoid*)g, (svoid*)l, 16, 0, 0);
}

// ---------------------------------------------------------------------------
// prep_w: transpose + f16-convert + tile + swizzle the enc-half of attn_w.
// Tile t = ks*2 + npass; tile = LDS image of the [512 n][32 k] chunk:
// 16B block p = nloc*4 + ((kblk + (nloc>>1)) & 3).
// ---------------------------------------------------------------------------
__global__ __launch_bounds__(256) void prep_w(const float* __restrict__ w,
                                              f16* __restrict__ wt) {
    int idx   = blockIdx.x * 256 + threadIdx.x;   // 0..131071
    int t     = idx >> 11;                        // tile 0..63
    int unit  = idx & 2047;
    int nloc  = unit >> 2;                        // 0..511
    int kblk  = unit & 3;
    int kstep = t >> 1, npass = t & 1;
    int n_g   = npass * 512 + nloc;
    int kbase = kstep * 32 + kblk * 8;
    half8 h;
#pragma unroll
    for (int kk = 0; kk < 8; ++kk)
        h[kk] = (f16)w[(size_t)(1024 + kbase + kk) * 1024 + n_g];
    int p = nloc * 4 + ((kblk + (nloc >> 1)) & 3);
    *(half8*)&wt[(size_t)t * 16384 + p * 8] = h;
}

// ---------------------------------------------------------------------------
// prep_hb: hb[b][n] = attn_b[n] + sum_k hidden[b][k] * attn_w[k][n]  (f32)
// ---------------------------------------------------------------------------
__global__ __launch_bounds__(256) void prep_hb(const float* __restrict__ hidden,
                                               const float* __restrict__ attn_w,
                                               const float* __restrict__ attn_b,
                                               float* __restrict__ hb) {
    int b = blockIdx.x >> 2;
    int n = (blockIdx.x & 3) * 256 + threadIdx.x;
    const float* h = hidden + (size_t)b * 1024;
    float acc = attn_b[n];
#pragma unroll 8
    for (int k = 0; k < 1024; ++k)
        acc += h[k] * attn_w[(size_t)k * 1024 + n];
    hb[(size_t)b * 1024 + n] = acc;
}

// ---------------------------------------------------------------------------
// fused_energy: per wg 64 flat rows of enc; 2 N-passes of 512; BK=32.
// 4 waves (1M x 4N), wave tile 64x128, frags 4(M) x 8(N), acc 128 f32/thread.
// Double-buffered; 2 blocks/CU so one block's barrier drain hides under the
// other block's MFMA phase.
// ---------------------------------------------------------------------------
__global__ __launch_bounds__(256, 2)
void fused_energy(const float* __restrict__ enc, const f16* __restrict__ wt,
                  const float* __restrict__ hb, const float* __restrict__ vvec,
                  float* __restrict__ out) {
    __shared__ f16 Ws[2][512 * 32];   // 2 x 32 KB, swizzled 16B blocks
    __shared__ f16 As[2][64 * 32];    // 2 x 4 KB, swizzled 16B blocks
    __shared__ float red[4][64];      // cross-wave score partials

    const int tid  = threadIdx.x;
    const int lane = tid & 63;
    const int wv   = tid >> 6;     // 0..3 (= wn; wm == 0)
    const int l15  = lane & 15;
    const int l4   = lane >> 4;
    const int wgrow = blockIdx.x * 64;

    // A staging: thread -> (row, kblk), 8 f32 -> 8 f16, one ds_write_b128
    const int ar  = tid >> 2;      // 0..63
    const int akb = tid & 3;
    const float* aG = enc + (size_t)(wgrow + ar) * KDIM + akb * 8;
    const int aDstByte = (ar * 4 + ((akb + (ar >> 1)) & 3)) * 16;

    // W staging: wave wv owns 8 x 1KB segments via global_load_lds(16B)
    const int wLdsOff = wv * 8192 + lane * 16;   // byte offset within Ws[buf]

    // fragment LDS byte offsets (swizzled)
    int aOffB[4], bOffB[8];
#pragma unroll
    for (int mi = 0; mi < 4; ++mi) {
        int r = mi * 16 + l15;
        aOffB[mi] = (r * 4 + ((l4 + (r >> 1)) & 3)) * 16;
    }
#pragma unroll
    for (int nj = 0; nj < 8; ++nj) {
        int n = wv * 128 + nj * 16 + l15;
        bOffB[nj] = (n * 4 + ((l4 + (n >> 1)) & 3)) * 16;
    }

    float part[4][4];
#pragma unroll
    for (int mi = 0; mi < 4; ++mi)
#pragma unroll
        for (int rg = 0; rg < 4; ++rg) part[mi][rg] = 0.f;

    const f32x4 zero = {0.f, 0.f, 0.f, 0.f};

    // ---- prologue: stage tile (pass=0, ks=0) into buf 0 ----
    {
        const char* wsrc = (const char*)wt + wLdsOff;   // tile 0
        char* wd = (char*)&Ws[0][0] + wLdsOff;
#pragma unroll
        for (int i = 0; i < 8; ++i)
            gload_lds16(wsrc + i * 1024, wd + i * 1024);
        f32x4 a0 = *(const f32x4*)(aG);
        f32x4 a1 = *(const f32x4*)(aG + 4);
        half8 ah;
#pragma unroll
        for (int j = 0; j < 4; ++j) { ah[j] = (f16)a0[j]; ah[4 + j] = (f16)a1[j]; }
        *(half8*)((char*)&As[0][0] + aDstByte) = ah;
    }
    __syncthreads();

    for (int pass = 0; pass < 2; ++pass) {
        f32x4 acc[4][8];
#pragma unroll
        for (int mi = 0; mi < 4; ++mi)
#pragma unroll
            for (int nj = 0; nj < 8; ++nj) acc[mi][nj] = zero;

#pragma unroll 2
        for (int ks = 0; ks < 32; ++ks) {
            const int cur = ks & 1;
            const int nxb = cur ^ 1;
            const int tn  = pass * 32 + ks + 1;    // next flat tile
            const bool pf = tn < 64;
            const int nks = tn & 31;
            const int nps = tn >> 5;

            f32x4 a0, a1;
            if (pf) {
                // issue next W tile's global_load_lds (latency hides under MFMA)
                const char* wsrc = (const char*)wt +
                    (size_t)(nks * 2 + nps) * 32768 + wLdsOff;
                char* wd = (char*)&Ws[nxb][0] + wLdsOff;
#pragma unroll
                for (int i = 0; i < 8; ++i)
                    gload_lds16(wsrc + i * 1024, wd + i * 1024);
                // issue next A f32 loads (A depends only on nks, not pass)
                a0 = *(const f32x4*)(aG + nks * 32);
                a1 = *(const f32x4*)(aG + nks * 32 + 4);
            }

            // ---- compute current tile from buf[cur] ----
            __builtin_amdgcn_s_setprio(1);
            half8 bf[8];
#pragma unroll
            for (int nj = 0; nj < 8; ++nj) bf[nj] = *(const half8*)((char*)&Ws[cur][0] + bOffB[nj]);
#pragma unroll
            for (int mi = 0; mi < 4; ++mi) {
                half8 af = *(const half8*)((char*)&As[cur][0] + aOffB[mi]);
#pragma unroll
                for (int nj = 0; nj < 8; ++nj)
                    acc[mi][nj] = __builtin_amdgcn_mfma_f32_16x16x32_f16(
                        af, bf[nj], acc[mi][nj], 0, 0, 0);
            }
            __builtin_amdgcn_s_setprio(0);

            if (pf) {
                half8 ah;
#pragma unroll
                for (int j = 0; j < 4; ++j) { ah[j] = (f16)a0[j]; ah[4 + j] = (f16)a1[j]; }
                *(half8*)((char*)&As[nxb][0] + aDstByte) = ah;
            }
            __syncthreads();   // drains vmcnt (W gload_lds) + lgkm (A ds_write)
        }

        // epilogue: e = acc + hb -> tanh -> * v, accumulate per-row partials
        const int nbase = pass * 512 + wv * 128;
        float vv[8];
#pragma unroll
        for (int nj = 0; nj < 8; ++nj) vv[nj] = vvec[nbase + nj * 16 + l15];
#pragma unroll
        for (int mi = 0; mi < 4; ++mi) {
#pragma unroll
            for (int rg = 0; rg < 4; ++rg) {
                int rl = mi * 16 + l4 * 4 + rg;          // local row 0..63
                const float* hbrow = hb + (size_t)(rl & 31) * NDIM + nbase + l15;
                float sum = 0.f;
#pragma unroll
                for (int nj = 0; nj < 8; ++nj) {
                    float e  = acc[mi][nj][rg] + hbrow[nj * 16];
                    float e2 = __expf(2.f * e);
                    float th = 1.f - 2.f / (e2 + 1.f);   // tanh(e)
                    sum += th * vv[nj];
                }
                part[mi][rg] += sum;
            }
        }
    }

    // reduce over the 16 lanes holding different n-columns of the same row
#pragma unroll
    for (int mi = 0; mi < 4; ++mi) {
#pragma unroll
        for (int rg = 0; rg < 4; ++rg) {
            float p = part[mi][rg];
            p += __shfl_xor(p, 1);
            p += __shfl_xor(p, 2);
            p += __shfl_xor(p, 4);
            p += __shfl_xor(p, 8);
            if (l15 == 0) red[wv][mi * 16 + l4 * 4 + rg] = p;
        }
    }
    __syncthreads();
    if (tid < 64) {
        float s = red[0][tid] + red[1][tid] + red[2][tid] + red[3][tid];
        int rG = wgrow + tid;                  // flat row = s*32 + b
        out[(size_t)(rG & 31) * SEQ + (rG >> 5)] = s;   // raw score -> out[b][s]
    }
}

// ---------------------------------------------------------------------------
// softmax over S=2048 per batch row, in-place on out
// ---------------------------------------------------------------------------
__global__ __launch_bounds__(256) void softmax_rows(float* __restrict__ out) {
    const int b = blockIdx.x;
    float* row = out + (size_t)b * SEQ;
    const int tid  = threadIdx.x;
    const int lane = tid & 63;
    const int wv   = tid >> 6;
    __shared__ float sred[4];
    __shared__ float ssum[4];
    float x[8];
    float mx = -3.4e38f;
#pragma unroll
    for (int j = 0; j < 8; ++j) { x[j] = row[tid + j * 256]; mx = fmaxf(mx, x[j]); }
#pragma unroll
    for (int o = 1; o < 64; o <<= 1) mx = fmaxf(mx, __shfl_xor(mx, o));
    if (lane == 0) sred[wv] = mx;
    __syncthreads();
    mx = fmaxf(fmaxf(sred[0], sred[1]), fmaxf(sred[2], sred[3]));
    float s = 0.f;
#pragma unroll
    for (int j = 0; j < 8; ++j) { x[j] = __expf(x[j] - mx); s += x[j]; }
#pragma unroll
    for (int o = 1; o < 64; o <<= 1) s += __shfl_xor(s, o);
    if (lane == 0) ssum[wv] = s;
    __syncthreads();
    s = ssum[0] + ssum[1] + ssum[2] + ssum[3];
    float inv = 1.f / s;
#pragma unroll
    for (int j = 0; j < 8; ++j) row[tid + j * 256] = x[j] * inv;
}

extern "C" void kernel_launch(void* const* d_in, const int* in_sizes, int n_in,
                              void* d_out, int out_size, void* d_ws, size_t ws_size,
                              hipStream_t stream) {
    const float* hidden = (const float*)d_in[0];   // [32][1024]
    const float* enc    = (const float*)d_in[1];   // [2048][32][1024]
    const float* attn_w = (const float*)d_in[2];   // [2048][1024]
    const float* attn_b = (const float*)d_in[3];   // [1024]
    const float* v      = (const float*)d_in[4];   // [1024]
    float* out = (float*)d_out;                    // [32][2048]

    f16*   wt = (f16*)d_ws;                        // 2 MB tiled/swizzled We
    float* hb = (float*)((char*)d_ws + (2u << 20)); // 128 KB

    prep_w<<<512, 256, 0, stream>>>(attn_w, wt);
    prep_hb<<<128, 256, 0, stream>>>(hidden, attn_w, attn_b, hb);
    fused_energy<<<1024, 256, 0, stream>>>(enc, wt, hb, v, out);
    softmax_rows<<<32, 256, 0, stream>>>(out);
}